// Round 17
// baseline (42.706 us; speedup 1.0000x reference)
//
#include <hip/hip_runtime.h>
#include <math.h>

#define NEXP 8
#define DIM 1024
#define NTOK 32768            // B*S = 8*4096
#define EPSF 1e-9f

#define K1_NB 1024            // 1024 blocks x 4 waves x 8 tokens = 32768
#define TPB 256               // 4 waves/block; (256,4) -> 56-64 VGPR envelope
#define FXSCALE 4294967296.0  // 2^32 fixed-point scale for deterministic atomics

// ---------------------------------------------------------------------------
// Single fused kernel = R16 (best, 31.3us) + in-kernel loss finalize via
// DEVICE-SCOPE ATOMICS ONLY (no __threadfence -- R12 proved per-block device
// fences cost ~100us on 8-XCD CDNA4 via forced L2 writebacks; atomics operate
// at the coherent point and need no flush):
//  - per-block loss partials -> 16 u64 fixed-point atomicAdds (scale 2^32;
//    integer adds are order-independent => deterministic across replays),
//  - __syncthreads() drains vmcnt(0) (compiler emits full waitcnt before
//    s_barrier) => adds complete before the counter bump,
//  - 1024th block reads accumulators with atomicAdd(ptr,0) (coherent reads,
//    16 lanes in parallel) and writes out[NTOK*9]. Deletes the finalize
//    kernel + graph launch gap (~4us).
// Everything else R16-verbatim: W (32KB) in LDS; half-0 x-loads + noise
// hoisted over the staging prologue; 4 half-iterations of the 2-token GEMV
// (56 VGPR, no spill); split butterfly; z parked in zlds immediately;
// barrier-free distributed epilogue (group g owns token t0+g).
// ---------------------------------------------------------------------------
__global__ __launch_bounds__(TPB, 4) void fused_kernel(
    const float* __restrict__ x, const float* __restrict__ W,
    const float* __restrict__ noise, float* __restrict__ out,
    unsigned long long* __restrict__ acc64, int* __restrict__ counter)
{
    __shared__ float4 Wlds[NEXP * DIM / 4];   // 2048 float4 = 32 KB
    __shared__ float  zlds[4][64];            // per-wave logits [token g][exp e]
    __shared__ float  wsum[4][16];            // per-wave loss stats
    __shared__ int    isLast;

    const int tid  = threadIdx.x;
    const int lane = tid & 63;
    const int wid  = tid >> 6;

    const int gw = (blockIdx.x << 2) + wid;   // wave id 0..4095
    const int t0 = gw << 3;                   // 8 tokens per wave

    // ---- hoist: noise for this wave's 8 tokens, coalesced, 1 VGPR
    const float nraw = noise[(size_t)t0 * NEXP + lane];

    // ---- hoist: half-0's x loads (2 tokens x 4 chunks, 32 VGPR, dead after
    //      h=0) — in flight during the W staging below
    float4 xh[2][4];
    #pragma unroll
    for (int j = 0; j < 2; ++j)
        #pragma unroll
        for (int p = 0; p < 4; ++p)
            xh[j][p] = *(const float4*)(x + (size_t)(t0 + j) * DIM + p * 256 + (lane << 2));

    const float4* Wg = (const float4*)W;
    #pragma unroll
    for (int i = 0; i < (NEXP * DIM / 4) / TPB; ++i)
        Wlds[tid + i * TPB] = Wg[tid + i * TPB];
    __syncthreads();

    const bool p0 = lane & 1;
    const bool p1 = (lane >> 1) & 1;
    const bool p2 = (lane >> 2) & 1;
    const int  e  = lane & 7;                 // expert this lane owns
    const int  g  = lane >> 3;                // token slot this lane serves

    #pragma unroll
    for (int h = 0; h < 4; ++h) {
        const int ta = t0 + h * 2;

        // R13-verbatim 2-token GEMV half-iteration (h=0 consumes the hoist)
        float4 xv[2][4];
        if (h == 0) {
            #pragma unroll
            for (int j = 0; j < 2; ++j)
                #pragma unroll
                for (int p = 0; p < 4; ++p) xv[j][p] = xh[j][p];
        } else {
            #pragma unroll
            for (int j = 0; j < 2; ++j)
                #pragma unroll
                for (int p = 0; p < 4; ++p)
                    xv[j][p] = *(const float4*)(x + (size_t)(ta + j) * DIM + p * 256 + (lane << 2));
        }

        float acc[2][NEXP];
        #pragma unroll
        for (int j = 0; j < 2; ++j)
            #pragma unroll
            for (int ee = 0; ee < NEXP; ++ee) acc[j][ee] = 0.f;

        #pragma unroll
        for (int p = 0; p < 4; ++p)
            #pragma unroll
            for (int ee = 0; ee < NEXP; ++ee) {
                float4 wv = Wlds[ee * 256 + p * 64 + lane];
                #pragma unroll
                for (int j = 0; j < 2; ++j)
                    acc[j][ee] += xv[j][p].x * wv.x + xv[j][p].y * wv.y
                                + xv[j][p].z * wv.z + xv[j][p].w * wv.w;
            }

        // split butterfly: 8 partials -> lane owns expert (lane&7)
        float k4[2][4];
        #pragma unroll
        for (int j = 0; j < 2; ++j)
            #pragma unroll
            for (int k = 0; k < 4; ++k) {
                float a = acc[j][2 * k], b = acc[j][2 * k + 1];
                float keep = p0 ? b : a, give = p0 ? a : b;
                k4[j][k] = keep + __shfl_xor(give, 1);
            }
        float k2v[2][2];
        #pragma unroll
        for (int j = 0; j < 2; ++j)
            #pragma unroll
            for (int k = 0; k < 2; ++k) {
                float a = k4[j][2 * k], b = k4[j][2 * k + 1];
                float keep = p1 ? b : a, give = p1 ? a : b;
                k2v[j][k] = keep + __shfl_xor(give, 2);
            }
        float z[2];
        #pragma unroll
        for (int j = 0; j < 2; ++j) {
            float a = k2v[j][0], b = k2v[j][1];
            float keep = p2 ? b : a, give = p2 ? a : b;
            z[j] = keep + __shfl_xor(give, 4);
        }
        #pragma unroll
        for (int j = 0; j < 2; ++j) {
            z[j] += __shfl_xor(z[j], 8);
            z[j] += __shfl_xor(z[j], 16);
            z[j] += __shfl_xor(z[j], 32);
        }

        // park immediately in LDS (keeps live-range tiny — the R13 property)
        if (lane < 16)
            zlds[wid][(h * 2 + (lane >> 3)) * 8 + (lane & 7)] = (lane >> 3) ? z[1] : z[0];
    }

    // ---- distributed epilogue (R13-proven), wave-local: NO barrier.
    float zv = zlds[wid][lane];               // = logit(token t0+g, expert e)

    const int t = t0 + g;

    // gumbel (noise hoisted at kernel start)
    zv += -logf(-logf(nraw + EPSF) + EPSF);

    // softmax within the 8-lane group
    float m = zv;
    m = fmaxf(m, __shfl_xor(m, 1));
    m = fmaxf(m, __shfl_xor(m, 2));
    m = fmaxf(m, __shfl_xor(m, 4));
    float ex = expf(zv - m);
    float sm = ex;
    sm += __shfl_xor(sm, 1);
    sm += __shfl_xor(sm, 2);
    sm += __shfl_xor(sm, 4);
    float score = ex / sm;

    // top-2 within the group (proven R1/R10/R13: value desc, lower idx ties)
    float b1v = score; int b1i = e;
    float b2v = -1.f;  int b2i = -1;
    #pragma unroll
    for (int d = 1; d < 8; d <<= 1) {
        float p1v = __shfl_xor(b1v, d); int p1i = __shfl_xor(b1i, d);
        float p2v = __shfl_xor(b2v, d); int p2i = __shfl_xor(b2i, d);
        if (p1v > b1v || (p1v == b1v && p1i < b1i)) {
            b2v = b1v; b2i = b1i;
            b1v = p1v; b1i = p1i;
        } else if (p1v > b2v || (p1v == b2v && p1i < b2i)) {
            b2v = p1v; b2i = p1i;
        }
        if (p2v > b2v || (p2v == b2v && p2i < b2i)) {
            b2v = p2v; b2i = p2i;
        }
    }

    // write dispatch-mask row (wave writes 72 contiguous floats)
    float mask = (e == b1i) ? b1v : ((e == b2i) ? b2v : 0.f);
    out[(size_t)t * 9 + 1 + e] = mask;
    if (e == 0) out[(size_t)t * 9] = 1.0f;

    // loss: sum score and score^2 across the 8 groups (= this wave's 8 tokens)
    float v1 = score, v2 = score * score;
    v1 += __shfl_xor(v1, 8);  v2 += __shfl_xor(v2, 8);
    v1 += __shfl_xor(v1, 16); v2 += __shfl_xor(v2, 16);
    v1 += __shfl_xor(v1, 32); v2 += __shfl_xor(v2, 32);
    if (lane < 8) { wsum[wid][lane] = v1; wsum[wid][8 + lane] = v2; }

    __syncthreads();

    // ---- block partial -> deterministic fixed-point atomic accumulate
    if (tid < 16) {
        float s = 0.f;
        #pragma unroll
        for (int w = 0; w < 4; ++w) s += wsum[w][tid];
        unsigned long long q = (unsigned long long)((double)s * FXSCALE);
        atomicAdd(&acc64[tid], q);            // device-scope, coherent point
    }
    __syncthreads();                          // drains vmcnt(0): adds complete

    if (tid == 0)
        isLast = (atomicAdd(counter, 1) == K1_NB - 1);
    __syncthreads();

    if (isLast) {
        // all 1024 blocks bumped the counter AFTER their adds completed =>
        // accumulators are final. Coherent read via atomicAdd(ptr, 0).
        if (tid < 16) {
            unsigned long long v = atomicAdd(&acc64[tid], 0ULL);
            float tot = (float)((double)v * (1.0 / FXSCALE));
            const float invN = 1.0f / (float)NTOK;
            float partner = __shfl_xor(tot, 8);    // pairs sum <-> sumsq
            float prod = (tot * invN) * (partner * invN);
            prod += __shfl_xor(prod, 1);
            prod += __shfl_xor(prod, 2);
            prod += __shfl_xor(prod, 4);
            if (tid == 0)
                out[(size_t)NTOK * 9] = prod * 64.0f;   // * E^2
        }
    }
}

extern "C" void kernel_launch(void* const* d_in, const int* in_sizes, int n_in,
                              void* d_out, int out_size, void* d_ws, size_t ws_size,
                              hipStream_t stream) {
    const float* x     = (const float*)d_in[0];
    const float* W     = (const float*)d_in[1];
    const float* noise = (const float*)d_in[2];
    float* out = (float*)d_out;

    unsigned long long* acc64 = (unsigned long long*)d_ws;     // 16 x u64
    int* counter = (int*)((char*)d_ws + 128);                  // 1 x int

    hipMemsetAsync(d_ws, 0, 256, stream);     // graph-capture safe (R11-proven)
    fused_kernel<<<K1_NB, TPB, 0, stream>>>(x, W, noise, out, acc64, counter);
}

// Round 18
// 31.109 us; speedup vs baseline: 1.3728x; 1.3728x over previous
//
#include <hip/hip_runtime.h>
#include <math.h>

#define NEXP 8
#define DIM 1024
#define NTOK 32768            // B*S = 8*4096
#define EPSF 1e-9f

#define K1_NB 1024            // 1024 blocks x 4 waves x 8 tokens = 32768
#define TPB 256               // 4 waves/block; (256,4) -> 56-64 VGPR envelope

// ---------------------------------------------------------------------------
// Fused kernel = R16 exactly (best measured: 31.3us). Ledger of bracketed
// alternatives (all measured worse): LDS-read halving null (R14), 32-wave
// occupancy -3us (R15), no-W-staging -11us (R8), 4-token register shapes
// spill (R7/R10/R11), single-kernel finalize via fence -100us (R12) or
// atomics -11us (R17).
//  (1) half-0's eight x-loads issued ABOVE the W staging loop -> first HBM
//      round-trip overlaps the 32KB global->LDS prologue + barrier.
//  (2) noise load hoisted to kernel start -> ~500cy latency overlaps GEMV.
// W (32KB) in LDS; 4 half-iterations of the 2-token GEMV (acc[2][8], 56
// VGPR, no spill); split butterfly; z parked in zlds immediately;
// barrier-free distributed epilogue (group g owns token t0+g); loss via
// cross-group shuffles -> wsum -> partials[block][16].
// ---------------------------------------------------------------------------
__global__ __launch_bounds__(TPB, 4) void fused_kernel(
    const float* __restrict__ x, const float* __restrict__ W,
    const float* __restrict__ noise, float* __restrict__ out,
    float* __restrict__ partials)
{
    __shared__ float4 Wlds[NEXP * DIM / 4];   // 2048 float4 = 32 KB
    __shared__ float  zlds[4][64];            // per-wave logits [token g][exp e]
    __shared__ float  wsum[4][16];            // per-wave loss stats

    const int tid  = threadIdx.x;
    const int lane = tid & 63;
    const int wid  = tid >> 6;

    const int gw = (blockIdx.x << 2) + wid;   // wave id 0..4095
    const int t0 = gw << 3;                   // 8 tokens per wave

    // ---- hoist (2): noise for this wave's 8 tokens, coalesced, 1 VGPR
    const float nraw = noise[(size_t)t0 * NEXP + lane];

    // ---- hoist (1): half-0's x loads (2 tokens x 4 chunks, 32 VGPR,
    //      dead after h=0) — in flight during the W staging below
    float4 xh[2][4];
    #pragma unroll
    for (int j = 0; j < 2; ++j)
        #pragma unroll
        for (int p = 0; p < 4; ++p)
            xh[j][p] = *(const float4*)(x + (size_t)(t0 + j) * DIM + p * 256 + (lane << 2));

    const float4* Wg = (const float4*)W;
    #pragma unroll
    for (int i = 0; i < (NEXP * DIM / 4) / TPB; ++i)
        Wlds[tid + i * TPB] = Wg[tid + i * TPB];
    __syncthreads();

    const bool p0 = lane & 1;
    const bool p1 = (lane >> 1) & 1;
    const bool p2 = (lane >> 2) & 1;
    const int  e  = lane & 7;                 // expert this lane owns
    const int  g  = lane >> 3;                // token slot this lane serves

    #pragma unroll
    for (int h = 0; h < 4; ++h) {
        const int ta = t0 + h * 2;

        // R13-verbatim 2-token GEMV half-iteration (h=0 consumes the hoist)
        float4 xv[2][4];
        if (h == 0) {
            #pragma unroll
            for (int j = 0; j < 2; ++j)
                #pragma unroll
                for (int p = 0; p < 4; ++p) xv[j][p] = xh[j][p];
        } else {
            #pragma unroll
            for (int j = 0; j < 2; ++j)
                #pragma unroll
                for (int p = 0; p < 4; ++p)
                    xv[j][p] = *(const float4*)(x + (size_t)(ta + j) * DIM + p * 256 + (lane << 2));
        }

        float acc[2][NEXP];
        #pragma unroll
        for (int j = 0; j < 2; ++j)
            #pragma unroll
            for (int ee = 0; ee < NEXP; ++ee) acc[j][ee] = 0.f;

        #pragma unroll
        for (int p = 0; p < 4; ++p)
            #pragma unroll
            for (int ee = 0; ee < NEXP; ++ee) {
                float4 wv = Wlds[ee * 256 + p * 64 + lane];
                #pragma unroll
                for (int j = 0; j < 2; ++j)
                    acc[j][ee] += xv[j][p].x * wv.x + xv[j][p].y * wv.y
                                + xv[j][p].z * wv.z + xv[j][p].w * wv.w;
            }

        // split butterfly: 8 partials -> lane owns expert (lane&7)
        float k4[2][4];
        #pragma unroll
        for (int j = 0; j < 2; ++j)
            #pragma unroll
            for (int k = 0; k < 4; ++k) {
                float a = acc[j][2 * k], b = acc[j][2 * k + 1];
                float keep = p0 ? b : a, give = p0 ? a : b;
                k4[j][k] = keep + __shfl_xor(give, 1);
            }
        float k2v[2][2];
        #pragma unroll
        for (int j = 0; j < 2; ++j)
            #pragma unroll
            for (int k = 0; k < 2; ++k) {
                float a = k4[j][2 * k], b = k4[j][2 * k + 1];
                float keep = p1 ? b : a, give = p1 ? a : b;
                k2v[j][k] = keep + __shfl_xor(give, 2);
            }
        float z[2];
        #pragma unroll
        for (int j = 0; j < 2; ++j) {
            float a = k2v[j][0], b = k2v[j][1];
            float keep = p2 ? b : a, give = p2 ? a : b;
            z[j] = keep + __shfl_xor(give, 4);
        }
        #pragma unroll
        for (int j = 0; j < 2; ++j) {
            z[j] += __shfl_xor(z[j], 8);
            z[j] += __shfl_xor(z[j], 16);
            z[j] += __shfl_xor(z[j], 32);
        }

        // park immediately in LDS (keeps live-range tiny — the R13 property)
        if (lane < 16)
            zlds[wid][(h * 2 + (lane >> 3)) * 8 + (lane & 7)] = (lane >> 3) ? z[1] : z[0];
    }

    // ---- distributed epilogue (R13-proven), wave-local: NO barrier.
    float zv = zlds[wid][lane];               // = logit(token t0+g, expert e)

    const int t = t0 + g;

    // gumbel (noise hoisted at kernel start)
    zv += -logf(-logf(nraw + EPSF) + EPSF);

    // softmax within the 8-lane group
    float m = zv;
    m = fmaxf(m, __shfl_xor(m, 1));
    m = fmaxf(m, __shfl_xor(m, 2));
    m = fmaxf(m, __shfl_xor(m, 4));
    float ex = expf(zv - m);
    float sm = ex;
    sm += __shfl_xor(sm, 1);
    sm += __shfl_xor(sm, 2);
    sm += __shfl_xor(sm, 4);
    float score = ex / sm;

    // top-2 within the group (proven R1/R10/R13: value desc, lower idx ties)
    float b1v = score; int b1i = e;
    float b2v = -1.f;  int b2i = -1;
    #pragma unroll
    for (int d = 1; d < 8; d <<= 1) {
        float p1v = __shfl_xor(b1v, d); int p1i = __shfl_xor(b1i, d);
        float p2v = __shfl_xor(b2v, d); int p2i = __shfl_xor(b2i, d);
        if (p1v > b1v || (p1v == b1v && p1i < b1i)) {
            b2v = b1v; b2i = b1i;
            b1v = p1v; b1i = p1i;
        } else if (p1v > b2v || (p1v == b2v && p1i < b2i)) {
            b2v = p1v; b2i = p1i;
        }
        if (p2v > b2v || (p2v == b2v && p2i < b2i)) {
            b2v = p2v; b2i = p2i;
        }
    }

    // write dispatch-mask row (wave writes 72 contiguous floats)
    float mask = (e == b1i) ? b1v : ((e == b2i) ? b2v : 0.f);
    out[(size_t)t * 9 + 1 + e] = mask;
    if (e == 0) out[(size_t)t * 9] = 1.0f;

    // loss: sum score and score^2 across the 8 groups (= this wave's 8 tokens)
    float v1 = score, v2 = score * score;
    v1 += __shfl_xor(v1, 8);  v2 += __shfl_xor(v2, 8);
    v1 += __shfl_xor(v1, 16); v2 += __shfl_xor(v2, 16);
    v1 += __shfl_xor(v1, 32); v2 += __shfl_xor(v2, 32);
    if (lane < 8) { wsum[wid][lane] = v1; wsum[wid][8 + lane] = v2; }

    __syncthreads();
    if (tid < 16) {
        float s = 0.f;
        #pragma unroll
        for (int w = 0; w < 4; ++w) s += wsum[w][tid];
        partials[blockIdx.x * 16 + tid] = s;
    }
}

// ---------------------------------------------------------------------------
// K2: finalize loss at out[NTOK*9] from 1024 x 16 partials (= 4096 float4).
// 256 threads; thread t loads 16 independent float4 (coalesced, all in
// flight). LDS reduce; final 16-lane shuffle product (proven R7/R13 math).
// ---------------------------------------------------------------------------
__global__ __launch_bounds__(256) void finalize_kernel(
    const float* __restrict__ partials, float* __restrict__ out)
{
    __shared__ float lds[256 * 4];
    const int t = threadIdx.x;
    const float4* p4 = (const float4*)partials;

    float4 a = make_float4(0.f, 0.f, 0.f, 0.f);
    #pragma unroll
    for (int i = 0; i < 16; ++i) {            // 16 independent float4 loads
        float4 v = p4[i * 256 + t];
        a.x += v.x; a.y += v.y; a.z += v.z; a.w += v.w;
    }
    *(float4*)&lds[t * 4] = a;
    __syncthreads();

    if (t < 16) {
        const int c = t >> 2, m = t & 3;      // stat t = 4c + m
        float tot = 0.f;
        #pragma unroll
        for (int q = 0; q < 64; ++q)
            tot += lds[(q * 4 + c) * 4 + m];
        // lanes 0..15 hold totals for the 16 stats
        const float invN = 1.0f / (float)NTOK;
        float partner = __shfl_xor(tot, 8);   // pairs sum <-> sumsq
        float prod = (tot * invN) * (partner * invN);
        prod += __shfl_xor(prod, 1);
        prod += __shfl_xor(prod, 2);
        prod += __shfl_xor(prod, 4);
        if (t == 0)
            out[(size_t)NTOK * 9] = prod * 64.0f;   // * E^2
    }
}

extern "C" void kernel_launch(void* const* d_in, const int* in_sizes, int n_in,
                              void* d_out, int out_size, void* d_ws, size_t ws_size,
                              hipStream_t stream) {
    const float* x     = (const float*)d_in[0];
    const float* W     = (const float*)d_in[1];
    const float* noise = (const float*)d_in[2];
    float* out = (float*)d_out;
    float* partials = (float*)d_ws;   // 1024*16 floats = 64 KB

    fused_kernel<<<K1_NB, TPB, 0, stream>>>(x, W, noise, out, partials);
    finalize_kernel<<<1, 256, 0, stream>>>(partials, out);
}